// Round 7
// baseline (688.011 us; speedup 1.0000x reference)
//
#include <hip/hip_runtime.h>
#include <hip/hip_bf16.h>

typedef __bf16 bf16;
typedef _Float16 f16;
typedef __bf16 bf16x4 __attribute__((ext_vector_type(4)));
typedef __bf16 bf16x8 __attribute__((ext_vector_type(8)));
typedef _Float16 f16x4 __attribute__((ext_vector_type(4)));
typedef _Float16 f16x8 __attribute__((ext_vector_type(8)));
typedef float floatx4 __attribute__((ext_vector_type(4)));

static __device__ __forceinline__ floatx4 mfma_bf16(bf16x8 a, bf16x8 b, floatx4 c) {
  return __builtin_amdgcn_mfma_f32_16x16x32_bf16(a, b, c, 0, 0, 0);
}
static __device__ __forceinline__ floatx4 mfma_f16k32(f16x8 a, f16x8 b, floatx4 c) {
  return __builtin_amdgcn_mfma_f32_16x16x32_f16(a, b, c, 0, 0, 0);
}

// async global->LDS, 16B per lane; LDS dest = wave-uniform base + lane*16
static __device__ __forceinline__ void async16(void* lds, const void* gp) {
  __builtin_amdgcn_global_load_lds(
      (const __attribute__((address_space(1))) void*)gp,
      (__attribute__((address_space(3))) void*)lds, 16, 0, 0);
}

static __device__ __forceinline__ bf16x8 cvt8(float4 f0, float4 f1) {
  bf16x8 r;
  r[0] = (bf16)f0.x; r[1] = (bf16)f0.y; r[2] = (bf16)f0.z; r[3] = (bf16)f0.w;
  r[4] = (bf16)f1.x; r[5] = (bf16)f1.y; r[6] = (bf16)f1.z; r[7] = (bf16)f1.w;
  return r;
}

#define HEADS 8
#define DIMH 64
#define DIM 512
#define SEQ 4096
#define HALF 2048
#define BATCH 2
#define MROWS (BATCH * SEQ)          // 8192
#define ELEMS ((size_t)MROWS * DIM)  // 4194304 per tensor
#define NPARTS 4

// SCALE * log2(e), folded into Q at the qkv epilogue
#define C2F (0.044194173824159216f * 1.4426950408889634f)

// ---------------------------------------------------------------------------
// Kernel 0 (prep): one launch for Xb = (bf16)X, WtQKV = (bf16)Wqkv^T,
// WtOUT = (bf16)Wout^T.  Branch is uniform per block.
// ---------------------------------------------------------------------------
__global__ __launch_bounds__(256)
void prep(const float* __restrict__ X, bf16* __restrict__ Xb,
          const float* __restrict__ wqkv, bf16* __restrict__ W1t,
          const float* __restrict__ wout, bf16* __restrict__ W2t) {
  __shared__ float tile[32][33];
  const int bid = blockIdx.x, t = threadIdx.x;
  if (bid < 2048) {  // xcvt: 2048 blocks x 2048 elems
    size_t i = ((size_t)bid * 256 + t) * 8;
    float4 f0 = *reinterpret_cast<const float4*>(X + i);
    float4 f1 = *reinterpret_cast<const float4*>(X + i + 4);
    *reinterpret_cast<bf16x8*>(Xb + i) = cvt8(f0, f1);
    return;
  }
  const float* src; bf16* dst; int N, id;
  if (bid < 2816) { id = bid - 2048; src = wqkv; dst = W1t; N = 1536; }
  else            { id = bid - 2816; src = wout; dst = W2t; N = 512; }
  const int nb = N / 32;
  const int n0 = (id % nb) * 32, k0 = (id / nb) * 32;
  const int r = t >> 3, c4 = (t & 7) * 4;
  float4 v = *reinterpret_cast<const float4*>(src + (size_t)(k0 + r) * N + n0 + c4);
  tile[r][c4 + 0] = v.x; tile[r][c4 + 1] = v.y;
  tile[r][c4 + 2] = v.z; tile[r][c4 + 3] = v.w;
  __syncthreads();
  bf16x4 o;
#pragma unroll
  for (int i = 0; i < 4; ++i) o[i] = (bf16)tile[c4 + i][r];
  *reinterpret_cast<bf16x4*>(dst + (size_t)(n0 + r) * DIM + k0 + c4) = o;
}

// ---------------------------------------------------------------------------
// Kernel 1: qkv = Xb @ Wqkv.  m97 structure: 128x128 tile, BK=64, unpadded
// LDS, global_load_lds width-16 staging.  4 waves (2x2), 4x4 MFMA acc.
// Q (pre-scaled C2F), K -> [b][h][n][d] bf16; V -> Vt[b][h][d][n] f16.
// ---------------------------------------------------------------------------
__global__ __launch_bounds__(256)
void qkv_gemm(const bf16* __restrict__ Xb, const bf16* __restrict__ Wt,
              bf16* __restrict__ Qw, bf16* __restrict__ Kw, f16* __restrict__ Vt) {
  __shared__ __align__(16) char smem_raw[36864];
  bf16* Asf = (bf16*)smem_raw;             // [128][64] flat, 16 KB
  bf16* Bsf = (bf16*)(smem_raw + 16384);   // [128][64] flat, 16 KB

  const int m0 = blockIdx.x * 128, n0 = blockIdx.y * 128;
  const int t = threadIdx.x;
  const int wave = t >> 6, lane = t & 63, quad = lane >> 4, l16 = lane & 15;
  const int wr = wave >> 1, wc = wave & 1;

  f16 (*Ts)[72] = (f16(*)[72])(smem_raw + wave * 9216);  // epilogue alias

  floatx4 acc[4][4] = {};

  for (int k0 = 0; k0 < DIM; k0 += 64) {
    // granule g = it*256+t: row = g>>3, c8 = (g&7)*8; LDS byte = g*16
    // (lane-order contiguous -> satisfies wave-uniform-base + lane*16)
#pragma unroll
    for (int it = 0; it < 4; ++it) {
      int g = it * 256 + t, row = g >> 3, c8 = (g & 7) * 8;
      async16(Asf + (size_t)g * 8, Xb + (size_t)(m0 + row) * DIM + k0 + c8);
      async16(Bsf + (size_t)g * 8, Wt + (size_t)(n0 + row) * DIM + k0 + c8);
    }
    __syncthreads();  // drains vmcnt(0): LDS tiles ready

#pragma unroll
    for (int kk = 0; kk < 2; ++kk) {
      bf16x8 af[4], bfr[4];
#pragma unroll
      for (int mi = 0; mi < 4; ++mi)
        af[mi] = *reinterpret_cast<const bf16x8*>(
            Asf + (size_t)(wr * 64 + mi * 16 + l16) * 64 + kk * 32 + quad * 8);
#pragma unroll
      for (int ni = 0; ni < 4; ++ni)
        bfr[ni] = *reinterpret_cast<const bf16x8*>(
            Bsf + (size_t)(wc * 64 + ni * 16 + l16) * 64 + kk * 32 + quad * 8);
#pragma unroll
      for (int mi = 0; mi < 4; ++mi)
#pragma unroll
        for (int ni = 0; ni < 4; ++ni)
          acc[mi][ni] = mfma_bf16(af[mi], bfr[ni], acc[mi][ni]);
    }
    __syncthreads();  // all waves done reading before next overwrite
  }

  if (n0 < 1024) {  // pure Q or pure K tile
#pragma unroll
    for (int mi = 0; mi < 4; ++mi)
#pragma unroll
      for (int ni = 0; ni < 4; ++ni)
#pragma unroll
        for (int r = 0; r < 4; ++r) {
          int row = m0 + wr * 64 + mi * 16 + quad * 4 + r;
          int col = n0 + wc * 64 + ni * 16 + l16;
          int which = col >> 9, cc = col & 511;
          int head = cc >> 6, dim = cc & 63;
          int bb = row >> 12, nn = row & 4095;
          float val = acc[mi][ni][r];
          if (which == 0) val *= C2F;
          bf16* dst = which ? Kw : Qw;
          dst[(((size_t)(bb * HEADS + head)) * SEQ + nn) * DIMH + dim] = (bf16)val;
        }
  } else {  // V tile: per-wave 64x64 transpose through wave-private LDS
    int head = (n0 + wc * 64 - 1024) >> 6;
#pragma unroll
    for (int mi = 0; mi < 4; ++mi)
#pragma unroll
      for (int ni = 0; ni < 4; ++ni) {
        f16x4 pv;
#pragma unroll
        for (int r = 0; r < 4; ++r) pv[r] = (f16)acc[mi][ni][r];
        *reinterpret_cast<f16x4*>(&Ts[ni * 16 + l16][mi * 16 + quad * 4]) = pv;
      }
    int bb = m0 >> 12, nnb = (m0 + wr * 64) & 4095;
    size_t base = ((size_t)(bb * HEADS + head)) * DIMH;
#pragma unroll
    for (int it = 0; it < 8; ++it) {
      int idx = lane + it * 64;
      int d = idx >> 3, ns = (idx & 7) * 8;
      *reinterpret_cast<f16x8*>(Vt + (base + d) * SEQ + nnb + ns) =
          *reinterpret_cast<const f16x8*>(&Ts[d][ns]);
    }
  }
}

// ---------------------------------------------------------------------------
// Kernel 2: flash attention, KV-split-4.  Block = 128 queries (32/wave),
// part = quarter of the 2048 keys (512).  Grid 2048 -> 8 blocks/CU
// (LDS 18.4KB x 8 = 147KB, VGPR<=64 via launch_bounds(256,8)).
// Fixed-shift softmax: partials purely additive, combined in out_gemm.
// ---------------------------------------------------------------------------
__global__ __launch_bounds__(256, 8)
void attn_kernel(const bf16* __restrict__ Q, const bf16* __restrict__ K,
                 const f16* __restrict__ Vt, f16* __restrict__ Opart,
                 float* __restrict__ Lpart) {
  const int qt = blockIdx.x;                          // 0..31: 128-query tile
  const int h = blockIdx.y;
  const int bb = blockIdx.z >> 2, part = blockIdx.z & 3;
  const int t = threadIdx.x;
  const int wave = t >> 6, lane = t & 63, quad = lane >> 4, l16 = lane & 15;

  __shared__ bf16 Ks[64][72];   // [perm key][d]
  __shared__ f16 VsT[64][72];   // [d][key]

  const size_t hb = ((size_t)(bb * HEADS + h)) * SEQ * DIMH;
  const int vhalf = (qt < 16) ? 0 : HALF;   // v_s for first-half queries
  const int kstart = HALF + part * 512;     // keys always from k_t
  const int vstart = vhalf + part * 512;
  const int q0 = qt * 128 + wave * 32;

  // Q fragments (pre-scaled by C2F)
  bf16x8 qa[2][2];
#pragma unroll
  for (int mt = 0; mt < 2; ++mt)
#pragma unroll
    for (int kc = 0; kc < 2; ++kc)
      qa[mt][kc] = *reinterpret_cast<const bf16x8*>(
          Q + hb + (size_t)(q0 + mt * 16 + l16) * DIMH + kc * 32 + quad * 8);

  floatx4 o_acc[2][4] = {};   // O^T[d=dsub*16+quad*4+r][query=l16] per mt
  float l_acc[2] = {0.f, 0.f};

  // staging indices; sigma permutes K rows per 32-key group:
  // key w=8q+j (j<4) -> m=4q+j; (j>=4) -> m=16+4q+(j-4); row = 32g+m
  int srow[2], sdst[2], g8s;
  {
    int r0 = t >> 3;  g8s = (t & 7) * 8;
#pragma unroll
    for (int it = 0; it < 2; ++it) {
      int row = r0 + it * 32;
      int g32 = row >> 5, w = row & 31, q = w >> 3, j = w & 7;
      int m = (j < 4) ? (4 * q + j) : (16 + 4 * q + (j - 4));
      srow[it] = row;
      sdst[it] = 32 * g32 + m;
    }
  }

  bf16x8 kreg[2];
  f16x8 vreg[2];
  auto loadc = [&](int kc0) {
#pragma unroll
    for (int it = 0; it < 2; ++it) {
      kreg[it] = *reinterpret_cast<const bf16x8*>(
          K + hb + (size_t)(kstart + kc0 + srow[it]) * DIMH + g8s);
      vreg[it] = *reinterpret_cast<const f16x8*>(
          Vt + hb + (size_t)srow[it] * SEQ + vstart + kc0 + g8s);
    }
  };

  loadc(0);
  for (int kc0 = 0; kc0 < 512; kc0 += 64) {
    __syncthreads();
#pragma unroll
    for (int it = 0; it < 2; ++it) {
      *reinterpret_cast<bf16x8*>(&Ks[sdst[it]][g8s]) = kreg[it];
      *reinterpret_cast<f16x8*>(&VsT[srow[it]][g8s]) = vreg[it];
    }
    __syncthreads();
    int nxt = kc0 + 64; if (nxt >= 512) nxt = 0;
    loadc(nxt);

#pragma unroll
    for (int g = 0; g < 2; ++g) {  // 32-key groups
      bf16x8 kaA0 = *reinterpret_cast<const bf16x8*>(&Ks[g * 32 + l16][quad * 8]);
      bf16x8 kaA1 = *reinterpret_cast<const bf16x8*>(&Ks[g * 32 + l16][32 + quad * 8]);
      bf16x8 kaB0 = *reinterpret_cast<const bf16x8*>(&Ks[g * 32 + 16 + l16][quad * 8]);
      bf16x8 kaB1 = *reinterpret_cast<const bf16x8*>(&Ks[g * 32 + 16 + l16][32 + quad * 8]);

      f16x8 pbm[2];
#pragma unroll
      for (int mt = 0; mt < 2; ++mt) {
        floatx4 stA = {0.f, 0.f, 0.f, 0.f}, stB = {0.f, 0.f, 0.f, 0.f};
        stA = mfma_bf16(kaA0, qa[mt][0], stA);
        stA = mfma_bf16(kaA1, qa[mt][1], stA);
        stB = mfma_bf16(kaB0, qa[mt][0], stB);
        stB = mfma_bf16(kaB1, qa[mt][1], stB);
        float ls = l_acc[mt];
        f16x8 pb;
#pragma unroll
        for (int r = 0; r < 4; ++r) {
          float pA = __builtin_amdgcn_exp2f(stA[r]);
          float pB = __builtin_amdgcn_exp2f(stB[r]);
          ls += pA + pB;
          pb[r] = (f16)pA;
          pb[4 + r] = (f16)pB;
        }
        l_acc[mt] = ls;
        pbm[mt] = pb;
      }

#pragma unroll
      for (int dsub = 0; dsub < 4; ++dsub) {
        f16x8 va = *reinterpret_cast<const f16x8*>(
            &VsT[dsub * 16 + l16][g * 32 + quad * 8]);
        o_acc[0][dsub] = mfma_f16k32(va, pbm[0], o_acc[0][dsub]);
        o_acc[1][dsub] = mfma_f16k32(va, pbm[1], o_acc[1][dsub]);
      }
    }
  }

  // partial denominators + partial O out
  f16* Op = Opart + (size_t)part * ELEMS;
  float* Lp = Lpart + (size_t)part * MROWS * HEADS;
#pragma unroll
  for (int mt = 0; mt < 2; ++mt) {
    float v = l_acc[mt];
    v += __shfl_xor(v, 16);
    v += __shfl_xor(v, 32);
    int n = q0 + mt * 16 + l16;
    size_t rowidx = (size_t)(bb * SEQ + n);
    if (quad == 0) Lp[rowidx * HEADS + h] = v;
    size_t rowbase = rowidx * DIM + h * DIMH;
#pragma unroll
    for (int dsub = 0; dsub < 4; ++dsub) {
      f16x4 ov;
#pragma unroll
      for (int r = 0; r < 4; ++r) ov[r] = (f16)o_acc[mt][dsub][r];
      *reinterpret_cast<f16x4*>(Op + rowbase + dsub * 16 + quad * 4) = ov;
    }
  }
}

// ---------------------------------------------------------------------------
// Kernel 3: out = (sum_p O_p / sum_p L_p) @ Wout + b_out.  64x64 tile, BK=64,
// async B staging, combine fused into A-staging with O register prefetch.
// ---------------------------------------------------------------------------
__global__ __launch_bounds__(256)
void out_gemm(const f16* __restrict__ Opart, const float* __restrict__ Lpart,
              const bf16* __restrict__ Wt, const float* __restrict__ bias,
              float* __restrict__ out) {
  __shared__ __align__(16) bf16 Asf[64 * 64];   // [64][64] flat
  __shared__ __align__(16) bf16 Bsf[64 * 64];

  const int m0 = blockIdx.x * 64, n0 = blockIdx.y * 64;
  const int t = threadIdx.x;
  const int wave = t >> 6, lane = t & 63, quad = lane >> 4, l16 = lane & 15;
  const int m_off = (wave >> 1) * 32, n_off = (wave & 1) * 32;

  // per-thread staging coords (granule g = t + it*256)
  int srowi[2], sc8[2];
#pragma unroll
  for (int it = 0; it < 2; ++it) {
    int g = t + it * 256;
    srowi[it] = g >> 3; sc8[it] = (g & 7) * 8;
  }

  // preload 1/L per (staged row, head)
  float linv[2][8];
#pragma unroll
  for (int it = 0; it < 2; ++it) {
    size_t ar = (size_t)(m0 + srowi[it]);
#pragma unroll
    for (int hh = 0; hh < 8; ++hh) {
      float s = 0.f;
#pragma unroll
      for (int p = 0; p < NPARTS; ++p)
        s += Lpart[(size_t)p * MROWS * HEADS + ar * HEADS + hh];
      linv[it][hh] = 1.0f / s;
    }
  }

  floatx4 acc[2][2] = {};

  f16x8 oreg[2][NPARTS];
  auto loadO = [&](int k0) {
#pragma unroll
    for (int it = 0; it < 2; ++it) {
      size_t abase = (size_t)(m0 + srowi[it]) * DIM + k0 + sc8[it];
#pragma unroll
      for (int p = 0; p < NPARTS; ++p)
        oreg[it][p] = *reinterpret_cast<const f16x8*>(Opart + (size_t)p * ELEMS + abase);
    }
  };

  loadO(0);
  for (int k0 = 0; k0 < DIM; k0 += 64) {
#pragma unroll
    for (int it = 0; it < 2; ++it) {
      int g = t + it * 256;
      async16(Bsf + (size_t)g * 8, Wt + (size_t)(n0 + srowi[it]) * DIM + k0 + sc8[it]);
      float inv = linv[it][(k0 + sc8[it]) >> 6];
      bf16x8 a;
#pragma unroll
      for (int j = 0; j < 8; ++j)
        a[j] = (bf16)(((float)oreg[it][0][j] + (float)oreg[it][1][j] +
                       (float)oreg[it][2][j] + (float)oreg[it][3][j]) * inv);
      *reinterpret_cast<bf16x8*>(Asf + (size_t)g * 8) = a;
    }
    __syncthreads();  // drains async B + ds_writes
    int nk = k0 + 64; if (nk >= DIM) nk = 0;
    loadO(nk);  // prefetch next O slab during compute

#pragma unroll
    for (int kk = 0; kk < 2; ++kk) {
      bf16x8 a0 = *reinterpret_cast<const bf16x8*>(Asf + (size_t)(m_off + l16) * 64 + kk * 32 + quad * 8);
      bf16x8 a1 = *reinterpret_cast<const bf16x8*>(Asf + (size_t)(m_off + 16 + l16) * 64 + kk * 32 + quad * 8);
      bf16x8 b0 = *reinterpret_cast<const bf16x8*>(Bsf + (size_t)(n_off + l16) * 64 + kk * 32 + quad * 8);
      bf16x8 b1 = *reinterpret_cast<const bf16x8*>(Bsf + (size_t)(n_off + 16 + l16) * 64 + kk * 32 + quad * 8);
      acc[0][0] = mfma_bf16(a0, b0, acc[0][0]);
      acc[0][1] = mfma_bf16(a0, b1, acc[0][1]);
      acc[1][0] = mfma_bf16(a1, b0, acc[1][0]);
      acc[1][1] = mfma_bf16(a1, b1, acc[1][1]);
    }
    __syncthreads();
  }

#pragma unroll
  for (int mi = 0; mi < 2; ++mi)
#pragma unroll
    for (int ni = 0; ni < 2; ++ni)
#pragma unroll
      for (int r = 0; r < 4; ++r) {
        int row = m0 + m_off + mi * 16 + quad * 4 + r;
        int col = n0 + n_off + ni * 16 + l16;
        out[(size_t)row * DIM + col] = acc[mi][ni][r] + bias[col];
      }
}

extern "C" void kernel_launch(void* const* d_in, const int* in_sizes, int n_in,
                              void* d_out, int out_size, void* d_ws, size_t ws_size,
                              hipStream_t stream) {
  const float* x = (const float*)d_in[0];
  const float* wqkv = (const float*)d_in[1];
  const float* wout = (const float*)d_in[2];
  const float* bout = (const float*)d_in[3];
  float* out = (float*)d_out;

  char* ws = (char*)d_ws;
  f16* Opart = (f16*)ws;                     // 4 x 8 MB (part0 aliases Xb)
  bf16* Xb = (bf16*)ws;                      // 8 MB, consumed by qkv before attn
  bf16* Qw = (bf16*)(ws + ((size_t)32 << 20));  // 8 MB
  bf16* Kw = Qw + ELEMS;                     // 8 MB
  f16* Vt = (f16*)(Kw + ELEMS);              // 8 MB
  bf16* WtQKV = (bf16*)(Vt + ELEMS);         // 1.5 MB
  bf16* WtOUT = WtQKV + (size_t)1536 * 512;  // 0.5 MB
  float* Lpart = (float*)(WtOUT + (size_t)512 * 512);  // 4 x 256 KB

  prep<<<3072, 256, 0, stream>>>(x, Xb, wqkv, WtQKV, wout, WtOUT);
  qkv_gemm<<<dim3(MROWS / 128, 1536 / 128), 256, 0, stream>>>(Xb, WtQKV, Qw, Kw, Vt);
  attn_kernel<<<dim3(SEQ / 128, HEADS, BATCH * NPARTS), 256, 0, stream>>>(Qw, Kw, Vt, Opart, Lpart);
  out_gemm<<<dim3(MROWS / 64, DIM / 64), 256, 0, stream>>>(Opart, Lpart, WtOUT, bout, out);
}

// Round 8
// 178.434 us; speedup vs baseline: 3.8558x; 3.8558x over previous
//
#include <hip/hip_runtime.h>
#include <hip/hip_bf16.h>

typedef __bf16 bf16;
typedef _Float16 f16;
typedef __bf16 bf16x4 __attribute__((ext_vector_type(4)));
typedef __bf16 bf16x8 __attribute__((ext_vector_type(8)));
typedef _Float16 f16x4 __attribute__((ext_vector_type(4)));
typedef _Float16 f16x8 __attribute__((ext_vector_type(8)));
typedef float floatx4 __attribute__((ext_vector_type(4)));

static __device__ __forceinline__ floatx4 mfma_bf16(bf16x8 a, bf16x8 b, floatx4 c) {
  return __builtin_amdgcn_mfma_f32_16x16x32_bf16(a, b, c, 0, 0, 0);
}
static __device__ __forceinline__ floatx4 mfma_f16k32(f16x8 a, f16x8 b, floatx4 c) {
  return __builtin_amdgcn_mfma_f32_16x16x32_f16(a, b, c, 0, 0, 0);
}

// async global->LDS, 16B per lane; LDS dest = wave-uniform base + lane*16
static __device__ __forceinline__ void async16(void* lds, const void* gp) {
  __builtin_amdgcn_global_load_lds(
      (const __attribute__((address_space(1))) void*)gp,
      (__attribute__((address_space(3))) void*)lds, 16, 0, 0);
}

static __device__ __forceinline__ bf16x8 cvt8(float4 f0, float4 f1) {
  bf16x8 r;
  r[0] = (bf16)f0.x; r[1] = (bf16)f0.y; r[2] = (bf16)f0.z; r[3] = (bf16)f0.w;
  r[4] = (bf16)f1.x; r[5] = (bf16)f1.y; r[6] = (bf16)f1.z; r[7] = (bf16)f1.w;
  return r;
}

#define HEADS 8
#define DIMH 64
#define DIM 512
#define SEQ 4096
#define HALF 2048
#define BATCH 2
#define MROWS (BATCH * SEQ)          // 8192
#define ELEMS ((size_t)MROWS * DIM)  // 4194304 per tensor
#define NPARTS 4

// SCALE * log2(e), folded into Q at the qkv epilogue
#define C2F (0.044194173824159216f * 1.4426950408889634f)

// ---------------------------------------------------------------------------
// Kernel 0 (prep): one launch for Xb = (bf16)X, WtQKV = (bf16)Wqkv^T,
// WtOUT = (bf16)Wout^T.  Branch is uniform per block.
// ---------------------------------------------------------------------------
__global__ __launch_bounds__(256)
void prep(const float* __restrict__ X, bf16* __restrict__ Xb,
          const float* __restrict__ wqkv, bf16* __restrict__ W1t,
          const float* __restrict__ wout, bf16* __restrict__ W2t) {
  __shared__ float tile[32][33];
  const int bid = blockIdx.x, t = threadIdx.x;
  if (bid < 2048) {  // xcvt: 2048 blocks x 2048 elems
    size_t i = ((size_t)bid * 256 + t) * 8;
    float4 f0 = *reinterpret_cast<const float4*>(X + i);
    float4 f1 = *reinterpret_cast<const float4*>(X + i + 4);
    *reinterpret_cast<bf16x8*>(Xb + i) = cvt8(f0, f1);
    return;
  }
  const float* src; bf16* dst; int N, id;
  if (bid < 2816) { id = bid - 2048; src = wqkv; dst = W1t; N = 1536; }
  else            { id = bid - 2816; src = wout; dst = W2t; N = 512; }
  const int nb = N / 32;
  const int n0 = (id % nb) * 32, k0 = (id / nb) * 32;
  const int r = t >> 3, c4 = (t & 7) * 4;
  float4 v = *reinterpret_cast<const float4*>(src + (size_t)(k0 + r) * N + n0 + c4);
  tile[r][c4 + 0] = v.x; tile[r][c4 + 1] = v.y;
  tile[r][c4 + 2] = v.z; tile[r][c4 + 3] = v.w;
  __syncthreads();
  bf16x4 o;
#pragma unroll
  for (int i = 0; i < 4; ++i) o[i] = (bf16)tile[c4 + i][r];
  *reinterpret_cast<bf16x4*>(dst + (size_t)(n0 + r) * DIM + k0 + c4) = o;
}

// ---------------------------------------------------------------------------
// Kernel 1: qkv = Xb @ Wqkv.  m97 structure: 128x128 tile, BK=64, unpadded
// LDS, global_load_lds width-16 staging.  4 waves (2x2), 4x4 MFMA acc.
// Q (pre-scaled C2F), K -> [b][h][n][d] bf16; V -> Vt[b][h][d][n] f16.
// ---------------------------------------------------------------------------
__global__ __launch_bounds__(256)
void qkv_gemm(const bf16* __restrict__ Xb, const bf16* __restrict__ Wt,
              bf16* __restrict__ Qw, bf16* __restrict__ Kw, f16* __restrict__ Vt) {
  __shared__ __align__(16) char smem_raw[36864];
  bf16* Asf = (bf16*)smem_raw;             // [128][64] flat, 16 KB
  bf16* Bsf = (bf16*)(smem_raw + 16384);   // [128][64] flat, 16 KB

  const int m0 = blockIdx.x * 128, n0 = blockIdx.y * 128;
  const int t = threadIdx.x;
  const int wave = t >> 6, lane = t & 63, quad = lane >> 4, l16 = lane & 15;
  const int wr = wave >> 1, wc = wave & 1;

  f16 (*Ts)[72] = (f16(*)[72])(smem_raw + wave * 9216);  // epilogue alias

  floatx4 acc[4][4] = {};

  for (int k0 = 0; k0 < DIM; k0 += 64) {
    // granule g = it*256+t: row = g>>3, c8 = (g&7)*8; LDS byte = g*16
    // (lane-order contiguous -> satisfies wave-uniform-base + lane*16)
#pragma unroll
    for (int it = 0; it < 4; ++it) {
      int g = it * 256 + t, row = g >> 3, c8 = (g & 7) * 8;
      async16(Asf + (size_t)g * 8, Xb + (size_t)(m0 + row) * DIM + k0 + c8);
      async16(Bsf + (size_t)g * 8, Wt + (size_t)(n0 + row) * DIM + k0 + c8);
    }
    __syncthreads();  // drains vmcnt(0): LDS tiles ready

#pragma unroll
    for (int kk = 0; kk < 2; ++kk) {
      bf16x8 af[4], bfr[4];
#pragma unroll
      for (int mi = 0; mi < 4; ++mi)
        af[mi] = *reinterpret_cast<const bf16x8*>(
            Asf + (size_t)(wr * 64 + mi * 16 + l16) * 64 + kk * 32 + quad * 8);
#pragma unroll
      for (int ni = 0; ni < 4; ++ni)
        bfr[ni] = *reinterpret_cast<const bf16x8*>(
            Bsf + (size_t)(wc * 64 + ni * 16 + l16) * 64 + kk * 32 + quad * 8);
#pragma unroll
      for (int mi = 0; mi < 4; ++mi)
#pragma unroll
        for (int ni = 0; ni < 4; ++ni)
          acc[mi][ni] = mfma_bf16(af[mi], bfr[ni], acc[mi][ni]);
    }
    __syncthreads();  // all waves done reading before next overwrite
  }

  if (n0 < 1024) {  // pure Q or pure K tile
#pragma unroll
    for (int mi = 0; mi < 4; ++mi)
#pragma unroll
      for (int ni = 0; ni < 4; ++ni)
#pragma unroll
        for (int r = 0; r < 4; ++r) {
          int row = m0 + wr * 64 + mi * 16 + quad * 4 + r;
          int col = n0 + wc * 64 + ni * 16 + l16;
          int which = col >> 9, cc = col & 511;
          int head = cc >> 6, dim = cc & 63;
          int bb = row >> 12, nn = row & 4095;
          float val = acc[mi][ni][r];
          if (which == 0) val *= C2F;
          bf16* dst = which ? Kw : Qw;
          dst[(((size_t)(bb * HEADS + head)) * SEQ + nn) * DIMH + dim] = (bf16)val;
        }
  } else {  // V tile: per-wave 64x64 transpose through wave-private LDS
    int head = (n0 + wc * 64 - 1024) >> 6;
#pragma unroll
    for (int mi = 0; mi < 4; ++mi)
#pragma unroll
      for (int ni = 0; ni < 4; ++ni) {
        f16x4 pv;
#pragma unroll
        for (int r = 0; r < 4; ++r) pv[r] = (f16)acc[mi][ni][r];
        *reinterpret_cast<f16x4*>(&Ts[ni * 16 + l16][mi * 16 + quad * 4]) = pv;
      }
    int bb = m0 >> 12, nnb = (m0 + wr * 64) & 4095;
    size_t base = ((size_t)(bb * HEADS + head)) * DIMH;
#pragma unroll
    for (int it = 0; it < 8; ++it) {
      int idx = lane + it * 64;
      int d = idx >> 3, ns = (idx & 7) * 8;
      *reinterpret_cast<f16x8*>(Vt + (base + d) * SEQ + nnb + ns) =
          *reinterpret_cast<const f16x8*>(&Ts[d][ns]);
    }
  }
}

// ---------------------------------------------------------------------------
// Kernel 2: flash attention, KV-split-4.  Block = 128 queries (32/wave),
// part = quarter of the 2048 keys (512).  Grid 2048 -> up to 8 blocks/CU
// (LDS 18.4KB x 8 = 147KB; kernel is ~60 VGPR naturally, <= the 64 needed
// for 8 waves/SIMD -- NO register-forcing launch_bounds: round 7 showed
// launch_bounds(256,8) makes the allocator spill accumulators to scratch,
// 2 GB of HBM spill traffic, 12x slowdown).
// Fixed-shift softmax: partials purely additive, combined in out_gemm.
// ---------------------------------------------------------------------------
__global__ __launch_bounds__(256)
void attn_kernel(const bf16* __restrict__ Q, const bf16* __restrict__ K,
                 const f16* __restrict__ Vt, f16* __restrict__ Opart,
                 float* __restrict__ Lpart) {
  const int qt = blockIdx.x;                          // 0..31: 128-query tile
  const int h = blockIdx.y;
  const int bb = blockIdx.z >> 2, part = blockIdx.z & 3;
  const int t = threadIdx.x;
  const int wave = t >> 6, lane = t & 63, quad = lane >> 4, l16 = lane & 15;

  __shared__ bf16 Ks[64][72];   // [perm key][d]
  __shared__ f16 VsT[64][72];   // [d][key]

  const size_t hb = ((size_t)(bb * HEADS + h)) * SEQ * DIMH;
  const int vhalf = (qt < 16) ? 0 : HALF;   // v_s for first-half queries
  const int kstart = HALF + part * 512;     // keys always from k_t
  const int vstart = vhalf + part * 512;
  const int q0 = qt * 128 + wave * 32;

  // Q fragments (pre-scaled by C2F)
  bf16x8 qa[2][2];
#pragma unroll
  for (int mt = 0; mt < 2; ++mt)
#pragma unroll
    for (int kc = 0; kc < 2; ++kc)
      qa[mt][kc] = *reinterpret_cast<const bf16x8*>(
          Q + hb + (size_t)(q0 + mt * 16 + l16) * DIMH + kc * 32 + quad * 8);

  floatx4 o_acc[2][4] = {};   // O^T[d=dsub*16+quad*4+r][query=l16] per mt
  float l_acc[2] = {0.f, 0.f};

  // staging indices; sigma permutes K rows per 32-key group:
  // key w=8q+j (j<4) -> m=4q+j; (j>=4) -> m=16+4q+(j-4); row = 32g+m
  int srow[2], sdst[2], g8s;
  {
    int r0 = t >> 3;  g8s = (t & 7) * 8;
#pragma unroll
    for (int it = 0; it < 2; ++it) {
      int row = r0 + it * 32;
      int g32 = row >> 5, w = row & 31, q = w >> 3, j = w & 7;
      int m = (j < 4) ? (4 * q + j) : (16 + 4 * q + (j - 4));
      srow[it] = row;
      sdst[it] = 32 * g32 + m;
    }
  }

  bf16x8 kreg[2];
  f16x8 vreg[2];
  auto loadc = [&](int kc0) {
#pragma unroll
    for (int it = 0; it < 2; ++it) {
      kreg[it] = *reinterpret_cast<const bf16x8*>(
          K + hb + (size_t)(kstart + kc0 + srow[it]) * DIMH + g8s);
      vreg[it] = *reinterpret_cast<const f16x8*>(
          Vt + hb + (size_t)srow[it] * SEQ + vstart + kc0 + g8s);
    }
  };

  loadc(0);
  for (int kc0 = 0; kc0 < 512; kc0 += 64) {
    __syncthreads();
#pragma unroll
    for (int it = 0; it < 2; ++it) {
      *reinterpret_cast<bf16x8*>(&Ks[sdst[it]][g8s]) = kreg[it];
      *reinterpret_cast<f16x8*>(&VsT[srow[it]][g8s]) = vreg[it];
    }
    __syncthreads();
    int nxt = kc0 + 64; if (nxt >= 512) nxt = 0;
    loadc(nxt);

#pragma unroll
    for (int g = 0; g < 2; ++g) {  // 32-key groups
      bf16x8 kaA0 = *reinterpret_cast<const bf16x8*>(&Ks[g * 32 + l16][quad * 8]);
      bf16x8 kaA1 = *reinterpret_cast<const bf16x8*>(&Ks[g * 32 + l16][32 + quad * 8]);
      bf16x8 kaB0 = *reinterpret_cast<const bf16x8*>(&Ks[g * 32 + 16 + l16][quad * 8]);
      bf16x8 kaB1 = *reinterpret_cast<const bf16x8*>(&Ks[g * 32 + 16 + l16][32 + quad * 8]);

      f16x8 pbm[2];
#pragma unroll
      for (int mt = 0; mt < 2; ++mt) {
        floatx4 stA = {0.f, 0.f, 0.f, 0.f}, stB = {0.f, 0.f, 0.f, 0.f};
        stA = mfma_bf16(kaA0, qa[mt][0], stA);
        stA = mfma_bf16(kaA1, qa[mt][1], stA);
        stB = mfma_bf16(kaB0, qa[mt][0], stB);
        stB = mfma_bf16(kaB1, qa[mt][1], stB);
        float ls = l_acc[mt];
        f16x8 pb;
#pragma unroll
        for (int r = 0; r < 4; ++r) {
          float pA = __builtin_amdgcn_exp2f(stA[r]);
          float pB = __builtin_amdgcn_exp2f(stB[r]);
          ls += pA + pB;
          pb[r] = (f16)pA;
          pb[4 + r] = (f16)pB;
        }
        l_acc[mt] = ls;
        pbm[mt] = pb;
      }

#pragma unroll
      for (int dsub = 0; dsub < 4; ++dsub) {
        f16x8 va = *reinterpret_cast<const f16x8*>(
            &VsT[dsub * 16 + l16][g * 32 + quad * 8]);
        o_acc[0][dsub] = mfma_f16k32(va, pbm[0], o_acc[0][dsub]);
        o_acc[1][dsub] = mfma_f16k32(va, pbm[1], o_acc[1][dsub]);
      }
    }
  }

  // partial denominators + partial O out
  f16* Op = Opart + (size_t)part * ELEMS;
  float* Lp = Lpart + (size_t)part * MROWS * HEADS;
#pragma unroll
  for (int mt = 0; mt < 2; ++mt) {
    float v = l_acc[mt];
    v += __shfl_xor(v, 16);
    v += __shfl_xor(v, 32);
    int n = q0 + mt * 16 + l16;
    size_t rowidx = (size_t)(bb * SEQ + n);
    if (quad == 0) Lp[rowidx * HEADS + h] = v;
    size_t rowbase = rowidx * DIM + h * DIMH;
#pragma unroll
    for (int dsub = 0; dsub < 4; ++dsub) {
      f16x4 ov;
#pragma unroll
      for (int r = 0; r < 4; ++r) ov[r] = (f16)o_acc[mt][dsub][r];
      *reinterpret_cast<f16x4*>(Op + rowbase + dsub * 16 + quad * 4) = ov;
    }
  }
}

// ---------------------------------------------------------------------------
// Kernel 3: out = (sum_p O_p / sum_p L_p) @ Wout + b_out.  64x64 tile, BK=64,
// async B staging, combine fused into A-staging with O register prefetch.
// ---------------------------------------------------------------------------
__global__ __launch_bounds__(256)
void out_gemm(const f16* __restrict__ Opart, const float* __restrict__ Lpart,
              const bf16* __restrict__ Wt, const float* __restrict__ bias,
              float* __restrict__ out) {
  __shared__ __align__(16) bf16 Asf[64 * 64];   // [64][64] flat
  __shared__ __align__(16) bf16 Bsf[64 * 64];

  const int m0 = blockIdx.x * 64, n0 = blockIdx.y * 64;
  const int t = threadIdx.x;
  const int wave = t >> 6, lane = t & 63, quad = lane >> 4, l16 = lane & 15;
  const int m_off = (wave >> 1) * 32, n_off = (wave & 1) * 32;

  // per-thread staging coords (granule g = t + it*256)
  int srowi[2], sc8[2];
#pragma unroll
  for (int it = 0; it < 2; ++it) {
    int g = t + it * 256;
    srowi[it] = g >> 3; sc8[it] = (g & 7) * 8;
  }

  // preload 1/L per (staged row, head)
  float linv[2][8];
#pragma unroll
  for (int it = 0; it < 2; ++it) {
    size_t ar = (size_t)(m0 + srowi[it]);
#pragma unroll
    for (int hh = 0; hh < 8; ++hh) {
      float s = 0.f;
#pragma unroll
      for (int p = 0; p < NPARTS; ++p)
        s += Lpart[(size_t)p * MROWS * HEADS + ar * HEADS + hh];
      linv[it][hh] = 1.0f / s;
    }
  }

  floatx4 acc[2][2] = {};

  f16x8 oreg[2][NPARTS];
  auto loadO = [&](int k0) {
#pragma unroll
    for (int it = 0; it < 2; ++it) {
      size_t abase = (size_t)(m0 + srowi[it]) * DIM + k0 + sc8[it];
#pragma unroll
      for (int p = 0; p < NPARTS; ++p)
        oreg[it][p] = *reinterpret_cast<const f16x8*>(Opart + (size_t)p * ELEMS + abase);
    }
  };

  loadO(0);
  for (int k0 = 0; k0 < DIM; k0 += 64) {
#pragma unroll
    for (int it = 0; it < 2; ++it) {
      int g = t + it * 256;
      async16(Bsf + (size_t)g * 8, Wt + (size_t)(n0 + srowi[it]) * DIM + k0 + sc8[it]);
      float inv = linv[it][(k0 + sc8[it]) >> 6];
      bf16x8 a;
#pragma unroll
      for (int j = 0; j < 8; ++j)
        a[j] = (bf16)(((float)oreg[it][0][j] + (float)oreg[it][1][j] +
                       (float)oreg[it][2][j] + (float)oreg[it][3][j]) * inv);
      *reinterpret_cast<bf16x8*>(Asf + (size_t)g * 8) = a;
    }
    __syncthreads();  // drains async B + ds_writes
    int nk = k0 + 64; if (nk >= DIM) nk = 0;
    loadO(nk);  // prefetch next O slab during compute

#pragma unroll
    for (int kk = 0; kk < 2; ++kk) {
      bf16x8 a0 = *reinterpret_cast<const bf16x8*>(Asf + (size_t)(m_off + l16) * 64 + kk * 32 + quad * 8);
      bf16x8 a1 = *reinterpret_cast<const bf16x8*>(Asf + (size_t)(m_off + 16 + l16) * 64 + kk * 32 + quad * 8);
      bf16x8 b0 = *reinterpret_cast<const bf16x8*>(Bsf + (size_t)(n_off + l16) * 64 + kk * 32 + quad * 8);
      bf16x8 b1 = *reinterpret_cast<const bf16x8*>(Bsf + (size_t)(n_off + 16 + l16) * 64 + kk * 32 + quad * 8);
      acc[0][0] = mfma_bf16(a0, b0, acc[0][0]);
      acc[0][1] = mfma_bf16(a0, b1, acc[0][1]);
      acc[1][0] = mfma_bf16(a1, b0, acc[1][0]);
      acc[1][1] = mfma_bf16(a1, b1, acc[1][1]);
    }
    __syncthreads();
  }

#pragma unroll
  for (int mi = 0; mi < 2; ++mi)
#pragma unroll
    for (int ni = 0; ni < 2; ++ni)
#pragma unroll
      for (int r = 0; r < 4; ++r) {
        int row = m0 + m_off + mi * 16 + quad * 4 + r;
        int col = n0 + n_off + ni * 16 + l16;
        out[(size_t)row * DIM + col] = acc[mi][ni][r] + bias[col];
      }
}

extern "C" void kernel_launch(void* const* d_in, const int* in_sizes, int n_in,
                              void* d_out, int out_size, void* d_ws, size_t ws_size,
                              hipStream_t stream) {
  const float* x = (const float*)d_in[0];
  const float* wqkv = (const float*)d_in[1];
  const float* wout = (const float*)d_in[2];
  const float* bout = (const float*)d_in[3];
  float* out = (float*)d_out;

  char* ws = (char*)d_ws;
  f16* Opart = (f16*)ws;                     // 4 x 8 MB (part0 aliases Xb)
  bf16* Xb = (bf16*)ws;                      // 8 MB, consumed by qkv before attn
  bf16* Qw = (bf16*)(ws + ((size_t)32 << 20));  // 8 MB
  bf16* Kw = Qw + ELEMS;                     // 8 MB
  f16* Vt = (f16*)(Kw + ELEMS);              // 8 MB
  bf16* WtQKV = (bf16*)(Vt + ELEMS);         // 1.5 MB
  bf16* WtOUT = WtQKV + (size_t)1536 * 512;  // 0.5 MB
  float* Lpart = (float*)(WtOUT + (size_t)512 * 512);  // 4 x 256 KB

  prep<<<3072, 256, 0, stream>>>(x, Xb, wqkv, WtQKV, wout, WtOUT);
  qkv_gemm<<<dim3(MROWS / 128, 1536 / 128), 256, 0, stream>>>(Xb, WtQKV, Qw, Kw, Vt);
  attn_kernel<<<dim3(SEQ / 128, HEADS, BATCH * NPARTS), 256, 0, stream>>>(Qw, Kw, Vt, Opart, Lpart);
  out_gemm<<<dim3(MROWS / 64, DIM / 64), 256, 0, stream>>>(Opart, Lpart, WtOUT, bout, out);
}

// Round 9
// 159.562 us; speedup vs baseline: 4.3119x; 1.1183x over previous
//
#include <hip/hip_runtime.h>
#include <hip/hip_bf16.h>

typedef __bf16 bf16;
typedef _Float16 f16;
typedef __bf16 bf16x4 __attribute__((ext_vector_type(4)));
typedef __bf16 bf16x8 __attribute__((ext_vector_type(8)));
typedef _Float16 f16x4 __attribute__((ext_vector_type(4)));
typedef _Float16 f16x8 __attribute__((ext_vector_type(8)));
typedef float floatx4 __attribute__((ext_vector_type(4)));

static __device__ __forceinline__ floatx4 mfma_bf16(bf16x8 a, bf16x8 b, floatx4 c) {
  return __builtin_amdgcn_mfma_f32_16x16x32_bf16(a, b, c, 0, 0, 0);
}
static __device__ __forceinline__ floatx4 mfma_f16k32(f16x8 a, f16x8 b, floatx4 c) {
  return __builtin_amdgcn_mfma_f32_16x16x32_f16(a, b, c, 0, 0, 0);
}

// async global->LDS, 16B per lane; LDS dest = wave-uniform base + lane*16
static __device__ __forceinline__ void async16(void* lds, const void* gp) {
  __builtin_amdgcn_global_load_lds(
      (const __attribute__((address_space(1))) void*)gp,
      (__attribute__((address_space(3))) void*)lds, 16, 0, 0);
}

static __device__ __forceinline__ bf16x8 cvt8(float4 f0, float4 f1) {
  bf16x8 r;
  r[0] = (bf16)f0.x; r[1] = (bf16)f0.y; r[2] = (bf16)f0.z; r[3] = (bf16)f0.w;
  r[4] = (bf16)f1.x; r[5] = (bf16)f1.y; r[6] = (bf16)f1.z; r[7] = (bf16)f1.w;
  return r;
}

#define HEADS 8
#define DIMH 64
#define DIM 512
#define SEQ 4096
#define HALF 2048
#define BATCH 2
#define MROWS (BATCH * SEQ)          // 8192
#define ELEMS ((size_t)MROWS * DIM)  // 4194304 per tensor
#define NPARTS 4

// SCALE * log2(e), folded into Q at the qkv epilogue
#define C2F (0.044194173824159216f * 1.4426950408889634f)

// ---------------------------------------------------------------------------
// Kernel 0 (prep): one launch for Xb = (bf16)X, WtQKV = (bf16)Wqkv^T,
// WtOUT = (bf16)Wout^T.  Branch is uniform per block.
// ---------------------------------------------------------------------------
__global__ __launch_bounds__(256)
void prep(const float* __restrict__ X, bf16* __restrict__ Xb,
          const float* __restrict__ wqkv, bf16* __restrict__ W1t,
          const float* __restrict__ wout, bf16* __restrict__ W2t) {
  __shared__ float tile[32][33];
  const int bid = blockIdx.x, t = threadIdx.x;
  if (bid < 2048) {  // xcvt: 2048 blocks x 2048 elems
    size_t i = ((size_t)bid * 256 + t) * 8;
    float4 f0 = *reinterpret_cast<const float4*>(X + i);
    float4 f1 = *reinterpret_cast<const float4*>(X + i + 4);
    *reinterpret_cast<bf16x8*>(Xb + i) = cvt8(f0, f1);
    return;
  }
  const float* src; bf16* dst; int N, id;
  if (bid < 2816) { id = bid - 2048; src = wqkv; dst = W1t; N = 1536; }
  else            { id = bid - 2816; src = wout; dst = W2t; N = 512; }
  const int nb = N / 32;
  const int n0 = (id % nb) * 32, k0 = (id / nb) * 32;
  const int r = t >> 3, c4 = (t & 7) * 4;
  float4 v = *reinterpret_cast<const float4*>(src + (size_t)(k0 + r) * N + n0 + c4);
  tile[r][c4 + 0] = v.x; tile[r][c4 + 1] = v.y;
  tile[r][c4 + 2] = v.z; tile[r][c4 + 3] = v.w;
  __syncthreads();
  bf16x4 o;
#pragma unroll
  for (int i = 0; i < 4; ++i) o[i] = (bf16)tile[c4 + i][r];
  *reinterpret_cast<bf16x4*>(dst + (size_t)(n0 + r) * DIM + k0 + c4) = o;
}

// ---------------------------------------------------------------------------
// Kernel 1: qkv = Xb @ Wqkv.  128x128 tile, DOUBLE-BUFFERED BK=32 async
// staging: issue next slab right after the barrier, compute overlaps the
// in-flight global_load_lds, so each barrier's vmcnt drain is covered by a
// full k-step of compute.  4 waves (2x2), 4x4 MFMA acc.
// Q (pre-scaled C2F), K -> [b][h][n][d] bf16; V -> Vt[b][h][d][n] f16.
// ---------------------------------------------------------------------------
__global__ __launch_bounds__(256)
void qkv_gemm(const bf16* __restrict__ Xb, const bf16* __restrict__ Wt,
              bf16* __restrict__ Qw, bf16* __restrict__ Kw, f16* __restrict__ Vt) {
  __shared__ __align__(16) char smem_raw[36864];
  // buf b: A at b*16384, B at b*16384+8192 (each 128x32 bf16 = 8 KB)

  const int m0 = blockIdx.x * 128, n0 = blockIdx.y * 128;
  const int t = threadIdx.x;
  const int wave = t >> 6, lane = t & 63, quad = lane >> 4, l16 = lane & 15;
  const int wr = wave >> 1, wc = wave & 1;

  f16 (*Ts)[72] = (f16(*)[72])(smem_raw + wave * 9216);  // epilogue alias

  floatx4 acc[4][4] = {};

  // granule g = it*256+t: row = g>>2, c8 = (g&3)*8; LDS byte = g*16
  // (lane-order contiguous -> wave-uniform base + lane*16)
  auto issue = [&](int buf, int k0) {
    bf16* Asf = (bf16*)(smem_raw + buf * 16384);
    bf16* Bsf = Asf + 4096;
#pragma unroll
    for (int it = 0; it < 2; ++it) {
      int g = it * 256 + t, row = g >> 2, c8 = (g & 3) * 8;
      async16(Asf + (size_t)g * 8, Xb + (size_t)(m0 + row) * DIM + k0 + c8);
      async16(Bsf + (size_t)g * 8, Wt + (size_t)(n0 + row) * DIM + k0 + c8);
    }
  };

  issue(0, 0);
  int buf = 0;
#pragma unroll 1
  for (int k0 = 0; k0 < DIM; k0 += 32) {
    __syncthreads();  // drains this buf's loads (issued last step, covered)
    if (k0 + 32 < DIM) issue(buf ^ 1, k0 + 32);

    const bf16* Asf = (const bf16*)(smem_raw + buf * 16384);
    const bf16* Bsf = Asf + 4096;
    bf16x8 af[4], bfr[4];
#pragma unroll
    for (int mi = 0; mi < 4; ++mi)
      af[mi] = *reinterpret_cast<const bf16x8*>(
          Asf + (size_t)(wr * 64 + mi * 16 + l16) * 32 + quad * 8);
#pragma unroll
    for (int ni = 0; ni < 4; ++ni)
      bfr[ni] = *reinterpret_cast<const bf16x8*>(
          Bsf + (size_t)(wc * 64 + ni * 16 + l16) * 32 + quad * 8);
#pragma unroll
    for (int mi = 0; mi < 4; ++mi)
#pragma unroll
      for (int ni = 0; ni < 4; ++ni)
        acc[mi][ni] = mfma_bf16(af[mi], bfr[ni], acc[mi][ni]);
    buf ^= 1;
  }

  if (n0 < 1024) {  // pure Q or pure K tile
#pragma unroll
    for (int mi = 0; mi < 4; ++mi)
#pragma unroll
      for (int ni = 0; ni < 4; ++ni)
#pragma unroll
        for (int r = 0; r < 4; ++r) {
          int row = m0 + wr * 64 + mi * 16 + quad * 4 + r;
          int col = n0 + wc * 64 + ni * 16 + l16;
          int which = col >> 9, cc = col & 511;
          int head = cc >> 6, dim = cc & 63;
          int bb = row >> 12, nn = row & 4095;
          float val = acc[mi][ni][r];
          if (which == 0) val *= C2F;
          bf16* dst = which ? Kw : Qw;
          dst[(((size_t)(bb * HEADS + head)) * SEQ + nn) * DIMH + dim] = (bf16)val;
        }
  } else {  // V tile: per-wave 64x64 transpose through wave-private LDS
    __syncthreads();  // all waves done with GEMM LDS before aliasing as Ts
    int head = (n0 + wc * 64 - 1024) >> 6;
#pragma unroll
    for (int mi = 0; mi < 4; ++mi)
#pragma unroll
      for (int ni = 0; ni < 4; ++ni) {
        f16x4 pv;
#pragma unroll
        for (int r = 0; r < 4; ++r) pv[r] = (f16)acc[mi][ni][r];
        *reinterpret_cast<f16x4*>(&Ts[ni * 16 + l16][mi * 16 + quad * 4]) = pv;
      }
    int bb = m0 >> 12, nnb = (m0 + wr * 64) & 4095;
    size_t base = ((size_t)(bb * HEADS + head)) * DIMH;
#pragma unroll
    for (int it = 0; it < 8; ++it) {
      int idx = lane + it * 64;
      int d = idx >> 3, ns = (idx & 7) * 8;
      *reinterpret_cast<f16x8*>(Vt + (base + d) * SEQ + nnb + ns) =
          *reinterpret_cast<const f16x8*>(&Ts[d][ns]);
    }
  }
}

// ---------------------------------------------------------------------------
// Kernel 2: flash attention, KV-split-4.  Block = 128 queries (32/wave),
// part = quarter of the 2048 keys (512).  Grid 2048 -> 8 blocks/CU
// (LDS 18.4KB x 8 = 147KB).  Key loop is FORCED ROLLED (#pragma unroll 1):
// round 8 showed full unroll of 8 iterations balloons VGPR 60->112 and
// halves occupancy.  No register-forcing launch_bounds (round 7: spills).
// Fixed-shift softmax: partials purely additive, combined in out_gemm.
// ---------------------------------------------------------------------------
__global__ __launch_bounds__(256)
void attn_kernel(const bf16* __restrict__ Q, const bf16* __restrict__ K,
                 const f16* __restrict__ Vt, f16* __restrict__ Opart,
                 float* __restrict__ Lpart) {
  const int qt = blockIdx.x;                          // 0..31: 128-query tile
  const int h = blockIdx.y;
  const int bb = blockIdx.z >> 2, part = blockIdx.z & 3;
  const int t = threadIdx.x;
  const int wave = t >> 6, lane = t & 63, quad = lane >> 4, l16 = lane & 15;

  __shared__ bf16 Ks[64][72];   // [perm key][d]
  __shared__ f16 VsT[64][72];   // [d][key]

  const size_t hb = ((size_t)(bb * HEADS + h)) * SEQ * DIMH;
  const int vhalf = (qt < 16) ? 0 : HALF;   // v_s for first-half queries
  const int kstart = HALF + part * 512;     // keys always from k_t
  const int vstart = vhalf + part * 512;
  const int q0 = qt * 128 + wave * 32;

  // Q fragments (pre-scaled by C2F)
  bf16x8 qa[2][2];
#pragma unroll
  for (int mt = 0; mt < 2; ++mt)
#pragma unroll
    for (int kc = 0; kc < 2; ++kc)
      qa[mt][kc] = *reinterpret_cast<const bf16x8*>(
          Q + hb + (size_t)(q0 + mt * 16 + l16) * DIMH + kc * 32 + quad * 8);

  floatx4 o_acc[2][4] = {};   // O^T[d=dsub*16+quad*4+r][query=l16] per mt
  float l_acc[2] = {0.f, 0.f};

  // staging indices; sigma permutes K rows per 32-key group:
  // key w=8q+j (j<4) -> m=4q+j; (j>=4) -> m=16+4q+(j-4); row = 32g+m
  int srow[2], sdst[2], g8s;
  {
    int r0 = t >> 3;  g8s = (t & 7) * 8;
#pragma unroll
    for (int it = 0; it < 2; ++it) {
      int row = r0 + it * 32;
      int g32 = row >> 5, w = row & 31, q = w >> 3, j = w & 7;
      int m = (j < 4) ? (4 * q + j) : (16 + 4 * q + (j - 4));
      srow[it] = row;
      sdst[it] = 32 * g32 + m;
    }
  }

  bf16x8 kreg[2];
  f16x8 vreg[2];
  auto loadc = [&](int kc0) {
#pragma unroll
    for (int it = 0; it < 2; ++it) {
      kreg[it] = *reinterpret_cast<const bf16x8*>(
          K + hb + (size_t)(kstart + kc0 + srow[it]) * DIMH + g8s);
      vreg[it] = *reinterpret_cast<const f16x8*>(
          Vt + hb + (size_t)srow[it] * SEQ + vstart + kc0 + g8s);
    }
  };

  loadc(0);
#pragma unroll 1
  for (int kc0 = 0; kc0 < 512; kc0 += 64) {
    __syncthreads();
#pragma unroll
    for (int it = 0; it < 2; ++it) {
      *reinterpret_cast<bf16x8*>(&Ks[sdst[it]][g8s]) = kreg[it];
      *reinterpret_cast<f16x8*>(&VsT[srow[it]][g8s]) = vreg[it];
    }
    __syncthreads();
    int nxt = kc0 + 64; if (nxt >= 512) nxt = 0;
    loadc(nxt);

#pragma unroll
    for (int g = 0; g < 2; ++g) {  // 32-key groups
      bf16x8 kaA0 = *reinterpret_cast<const bf16x8*>(&Ks[g * 32 + l16][quad * 8]);
      bf16x8 kaA1 = *reinterpret_cast<const bf16x8*>(&Ks[g * 32 + l16][32 + quad * 8]);
      bf16x8 kaB0 = *reinterpret_cast<const bf16x8*>(&Ks[g * 32 + 16 + l16][quad * 8]);
      bf16x8 kaB1 = *reinterpret_cast<const bf16x8*>(&Ks[g * 32 + 16 + l16][32 + quad * 8]);

      f16x8 pbm[2];
#pragma unroll
      for (int mt = 0; mt < 2; ++mt) {
        floatx4 stA = {0.f, 0.f, 0.f, 0.f}, stB = {0.f, 0.f, 0.f, 0.f};
        stA = mfma_bf16(kaA0, qa[mt][0], stA);
        stA = mfma_bf16(kaA1, qa[mt][1], stA);
        stB = mfma_bf16(kaB0, qa[mt][0], stB);
        stB = mfma_bf16(kaB1, qa[mt][1], stB);
        float ls = l_acc[mt];
        f16x8 pb;
#pragma unroll
        for (int r = 0; r < 4; ++r) {
          float pA = __builtin_amdgcn_exp2f(stA[r]);
          float pB = __builtin_amdgcn_exp2f(stB[r]);
          ls += pA + pB;
          pb[r] = (f16)pA;
          pb[4 + r] = (f16)pB;
        }
        l_acc[mt] = ls;
        pbm[mt] = pb;
      }

#pragma unroll
      for (int dsub = 0; dsub < 4; ++dsub) {
        f16x8 va = *reinterpret_cast<const f16x8*>(
            &VsT[dsub * 16 + l16][g * 32 + quad * 8]);
        o_acc[0][dsub] = mfma_f16k32(va, pbm[0], o_acc[0][dsub]);
        o_acc[1][dsub] = mfma_f16k32(va, pbm[1], o_acc[1][dsub]);
      }
    }
  }

  // partial denominators + partial O out
  f16* Op = Opart + (size_t)part * ELEMS;
  float* Lp = Lpart + (size_t)part * MROWS * HEADS;
#pragma unroll
  for (int mt = 0; mt < 2; ++mt) {
    float v = l_acc[mt];
    v += __shfl_xor(v, 16);
    v += __shfl_xor(v, 32);
    int n = q0 + mt * 16 + l16;
    size_t rowidx = (size_t)(bb * SEQ + n);
    if (quad == 0) Lp[rowidx * HEADS + h] = v;
    size_t rowbase = rowidx * DIM + h * DIMH;
#pragma unroll
    for (int dsub = 0; dsub < 4; ++dsub) {
      f16x4 ov;
#pragma unroll
      for (int r = 0; r < 4; ++r) ov[r] = (f16)o_acc[mt][dsub][r];
      *reinterpret_cast<f16x4*>(Op + rowbase + dsub * 16 + quad * 4) = ov;
    }
  }
}

// ---------------------------------------------------------------------------
// Kernel 3: out = (sum_p O_p / sum_p L_p) @ Wout + b_out.  64x64 tile, BK=64,
// async B staging, combine fused into A-staging with O register prefetch.
// ---------------------------------------------------------------------------
__global__ __launch_bounds__(256)
void out_gemm(const f16* __restrict__ Opart, const float* __restrict__ Lpart,
              const bf16* __restrict__ Wt, const float* __restrict__ bias,
              float* __restrict__ out) {
  __shared__ __align__(16) bf16 Asf[64 * 64];   // [64][64] flat
  __shared__ __align__(16) bf16 Bsf[64 * 64];

  const int m0 = blockIdx.x * 64, n0 = blockIdx.y * 64;
  const int t = threadIdx.x;
  const int wave = t >> 6, lane = t & 63, quad = lane >> 4, l16 = lane & 15;
  const int m_off = (wave >> 1) * 32, n_off = (wave & 1) * 32;

  // per-thread staging coords (granule g = t + it*256)
  int srowi[2], sc8[2];
#pragma unroll
  for (int it = 0; it < 2; ++it) {
    int g = t + it * 256;
    srowi[it] = g >> 3; sc8[it] = (g & 7) * 8;
  }

  // preload 1/L per (staged row, head)
  float linv[2][8];
#pragma unroll
  for (int it = 0; it < 2; ++it) {
    size_t ar = (size_t)(m0 + srowi[it]);
#pragma unroll
    for (int hh = 0; hh < 8; ++hh) {
      float s = 0.f;
#pragma unroll
      for (int p = 0; p < NPARTS; ++p)
        s += Lpart[(size_t)p * MROWS * HEADS + ar * HEADS + hh];
      linv[it][hh] = 1.0f / s;
    }
  }

  floatx4 acc[2][2] = {};

  f16x8 oreg[2][NPARTS];
  auto loadO = [&](int k0) {
#pragma unroll
    for (int it = 0; it < 2; ++it) {
      size_t abase = (size_t)(m0 + srowi[it]) * DIM + k0 + sc8[it];
#pragma unroll
      for (int p = 0; p < NPARTS; ++p)
        oreg[it][p] = *reinterpret_cast<const f16x8*>(Opart + (size_t)p * ELEMS + abase);
    }
  };

  loadO(0);
#pragma unroll 1
  for (int k0 = 0; k0 < DIM; k0 += 64) {
#pragma unroll
    for (int it = 0; it < 2; ++it) {
      int g = t + it * 256;
      async16(Bsf + (size_t)g * 8, Wt + (size_t)(n0 + srowi[it]) * DIM + k0 + sc8[it]);
      float inv = linv[it][(k0 + sc8[it]) >> 6];
      bf16x8 a;
#pragma unroll
      for (int j = 0; j < 8; ++j)
        a[j] = (bf16)(((float)oreg[it][0][j] + (float)oreg[it][1][j] +
                       (float)oreg[it][2][j] + (float)oreg[it][3][j]) * inv);
      *reinterpret_cast<bf16x8*>(Asf + (size_t)g * 8) = a;
    }
    __syncthreads();  // drains async B + ds_writes
    int nk = k0 + 64; if (nk >= DIM) nk = 0;
    loadO(nk);  // prefetch next O slab during compute

#pragma unroll
    for (int kk = 0; kk < 2; ++kk) {
      bf16x8 a0 = *reinterpret_cast<const bf16x8*>(Asf + (size_t)(m_off + l16) * 64 + kk * 32 + quad * 8);
      bf16x8 a1 = *reinterpret_cast<const bf16x8*>(Asf + (size_t)(m_off + 16 + l16) * 64 + kk * 32 + quad * 8);
      bf16x8 b0 = *reinterpret_cast<const bf16x8*>(Bsf + (size_t)(n_off + l16) * 64 + kk * 32 + quad * 8);
      bf16x8 b1 = *reinterpret_cast<const bf16x8*>(Bsf + (size_t)(n_off + 16 + l16) * 64 + kk * 32 + quad * 8);
      acc[0][0] = mfma_bf16(a0, b0, acc[0][0]);
      acc[0][1] = mfma_bf16(a0, b1, acc[0][1]);
      acc[1][0] = mfma_bf16(a1, b0, acc[1][0]);
      acc[1][1] = mfma_bf16(a1, b1, acc[1][1]);
    }
    __syncthreads();
  }

#pragma unroll
  for (int mi = 0; mi < 2; ++mi)
#pragma unroll
    for (int ni = 0; ni < 2; ++ni)
#pragma unroll
      for (int r = 0; r < 4; ++r) {
        int row = m0 + m_off + mi * 16 + quad * 4 + r;
        int col = n0 + n_off + ni * 16 + l16;
        out[(size_t)row * DIM + col] = acc[mi][ni][r] + bias[col];
      }
}

extern "C" void kernel_launch(void* const* d_in, const int* in_sizes, int n_in,
                              void* d_out, int out_size, void* d_ws, size_t ws_size,
                              hipStream_t stream) {
  const float* x = (const float*)d_in[0];
  const float* wqkv = (const float*)d_in[1];
  const float* wout = (const float*)d_in[2];
  const float* bout = (const float*)d_in[3];
  float* out = (float*)d_out;

  char* ws = (char*)d_ws;
  f16* Opart = (f16*)ws;                     // 4 x 8 MB (part0 aliases Xb)
  bf16* Xb = (bf16*)ws;                      // 8 MB, consumed by qkv before attn
  bf16* Qw = (bf16*)(ws + ((size_t)32 << 20));  // 8 MB
  bf16* Kw = Qw + ELEMS;                     // 8 MB
  f16* Vt = (f16*)(Kw + ELEMS);              // 8 MB
  bf16* WtQKV = (bf16*)(Vt + ELEMS);         // 1.5 MB
  bf16* WtOUT = WtQKV + (size_t)1536 * 512;  // 0.5 MB
  float* Lpart = (float*)(WtOUT + (size_t)512 * 512);  // 4 x 256 KB

  prep<<<3072, 256, 0, stream>>>(x, Xb, wqkv, WtQKV, wout, WtOUT);
  qkv_gemm<<<dim3(MROWS / 128, 1536 / 128), 256, 0, stream>>>(Xb, WtQKV, Qw, Kw, Vt);
  attn_kernel<<<dim3(SEQ / 128, HEADS, BATCH * NPARTS), 256, 0, stream>>>(Qw, Kw, Vt, Opart, Lpart);
  out_gemm<<<dim3(MROWS / 64, DIM / 64), 256, 0, stream>>>(Opart, Lpart, WtOUT, bout, out);
}